// Round 2
// baseline (148.751 us; speedup 1.0000x reference)
//
#include <hip/hip_runtime.h>
#include <stdint.h>

#define B_    8
#define N_    512
#define DIN   1024
#define DOUT  1024
#define L_    16
#define T_    4096

#define BM 256
#define BN 128
#define BK 64
#define NB (DOUT / BN)          /* 8 */
#define NKT (DIN / BK)          /* 16 K-tiles */
#define MT_MAX 144              /* 32768/256 + 16 partials */
#define ZROW ((long)B_ * N_)    /* zero-row index in pooled_bf16 */

typedef __attribute__((ext_vector_type(8))) short short8;
typedef __attribute__((ext_vector_type(4))) float f32x4;

/* ---- workspace layout (bytes) ----
   [0, WS_W)        pooled_bf16: B*N*DIN + one zero row
   [WS_W, WS_META)  W_bf16:      L*DOUT*DIN
   [WS_META, ...)   int meta: map[T], tlist[T], goff[16], grows[16],
                    table[MT_MAX], ntiles                                  */
#define POOLED_ELEMS ((long)B_ * N_ * DIN + DIN)
#define WS_W_OFF     ((size_t)POOLED_ELEMS * 2)
#define WS_META_OFF  (WS_W_OFF + (size_t)L_ * DOUT * DIN * 2)

__device__ __forceinline__ unsigned short f2bf(float f) {
  unsigned u = __float_as_uint(f);
  u += 0x7FFFu + ((u >> 16) & 1u);   /* RNE */
  return (unsigned short)(u >> 16);
}

__device__ __forceinline__ void gload_lds16(const void* g, void* l) {
  __builtin_amdgcn_global_load_lds(
      (const __attribute__((address_space(1))) void*)g,
      (__attribute__((address_space(3))) void*)l, 16, 0, 0);
}

__device__ __forceinline__ void bar() {
  asm volatile("" ::: "memory");
  __builtin_amdgcn_s_barrier();
  asm volatile("" ::: "memory");
}

/* ---------------- kernel 1: fp32 -> bf16 conversion ---------------- */
__global__ void k_convert(const float* __restrict__ pooled,
                          const float* __restrict__ W,
                          unsigned short* __restrict__ wsP,
                          unsigned short* __restrict__ wsW) {
  const long np4 = (long)B_ * N_ * DIN / 4;
  const long nw4 = (long)L_ * DOUT * DIN / 4;
  const long nz4 = DIN / 4;
  long i = (long)blockIdx.x * blockDim.x + threadIdx.x;
  const long stride = (long)gridDim.x * blockDim.x;
  for (; i < np4 + nw4 + nz4; i += stride) {
    if (i < np4) {
      float4 v = ((const float4*)pooled)[i];
      ushort4 o = { f2bf(v.x), f2bf(v.y), f2bf(v.z), f2bf(v.w) };
      ((ushort4*)wsP)[i] = o;
    } else if (i < np4 + nw4) {
      float4 v = ((const float4*)W)[i - np4];
      ushort4 o = { f2bf(v.x), f2bf(v.y), f2bf(v.z), f2bf(v.w) };
      ((ushort4*)wsW)[i - np4] = o;
    } else {
      ushort4 z = {0, 0, 0, 0};
      ((ushort4*)wsP)[i - nw4] = z;
    }
  }
}

/* ---------------- kernel 2: per-t (seg, lidx) map ---------------- */
__global__ void k_map(const int* __restrict__ pidx, int* __restrict__ map) {
  int t = blockIdx.x * blockDim.x + threadIdx.x;
  if (t >= T_) return;
  int lo = 0, hi = N_;
  while (lo < hi) {
    int mid = (lo + hi) >> 1;
    if (pidx[mid] < t) lo = mid + 1; else hi = mid;
  }
  int n, lidx;
  if (lo < N_) {
    int start = (lo > 0) ? (pidx[lo - 1] + 1) : 0;
    int li = t - start;
    lidx = li > (L_ - 1) ? (L_ - 1) : li;
    n = lo;
  } else {
    n = 0xFFFF;
    lidx = L_ - 1;
  }
  map[t] = n | (lidx << 16);
}

/* ---------------- kernel 3: group by lidx + tile table ---------------- */
__global__ void k_group(const int* __restrict__ map,
                        unsigned* __restrict__ tlist,
                        int* __restrict__ goff, int* __restrict__ grows,
                        unsigned* __restrict__ table, int* __restrict__ ntiles) {
  __shared__ int cnt[L_];
  __shared__ int pos[L_];
  int tid = threadIdx.x;
  if (tid < L_) cnt[tid] = 0;
  __syncthreads();
  for (int t = tid; t < T_; t += 256)
    atomicAdd(&cnt[(map[t] >> 16) & 0xFFFF], 1);
  __syncthreads();
  if (tid == 0) {
    int off = 0;
    for (int l = 0; l < L_; ++l) {
      pos[l] = off; goff[l] = off; grows[l] = cnt[l] * B_;
      off += cnt[l];
    }
  }
  __syncthreads();
  for (int t = tid; t < T_; t += 256) {
    int m = map[t];
    int l = (m >> 16) & 0xFFFF;
    int p = atomicAdd(&pos[l], 1);
    tlist[p] = (unsigned)t | ((unsigned)(m & 0xFFFF) << 16);
  }
  __syncthreads();
  if (tid == 0) {
    int tt = 0;
    for (int l = 0; l < L_; ++l) {
      int rows = cnt[l] * B_;
      for (int r0 = 0; r0 < rows; r0 += BM)
        table[tt++] = (unsigned)l | ((unsigned)r0 << 4);
    }
    *ntiles = tt;
  }
}

/* ---------------- kernel 4: grouped gather-GEMM, phase-interleaved ----------
   256x128 tile, BK=64, 8 waves (4M x 2N), 64x64 per wave.
   Triple-buffered LDS, depth-2 prefetch, counted vmcnt(6), T2 swizzle via
   pre-swizzled global source (linear gload_lds dest), T5 setprio.            */
__global__ __launch_bounds__(512, 1)
void k_gemm(const unsigned short* __restrict__ wsP,
            const unsigned short* __restrict__ wsW,
            const unsigned* __restrict__ tlist,
            const int* __restrict__ goff,
            const int* __restrict__ grows,
            const unsigned* __restrict__ table,
            const int* __restrict__ ntiles,
            float* __restrict__ out) {
  const int bid = blockIdx.x;
  const int mt = bid >> 3;           /* nt = bid&7 pins W panel to one XCD */
  const int nt = bid & 7;
  if (mt >= *ntiles) return;

  const unsigned te = table[mt];
  const int l    = te & 15;
  const int row0 = (int)(te >> 4);
  const int toff = goff[l];
  const int rows = grows[l];

  __shared__ __align__(16) unsigned short As[3][BM * BK];  /* 3 x 32 KiB */
  __shared__ __align__(16) unsigned short Bs[3][BN * BK];  /* 3 x 16 KiB */

  const int tid  = threadIdx.x;
  const int lane = tid & 63;
  const int w    = tid >> 6;      /* 0..7 */
  const int wm   = w >> 1;        /* 0..3 : M wave-row */
  const int wn   = w & 1;         /* 0..1 : N wave-col */

  /* ---- staging source pointers (inverse-swizzled slot on SOURCE) ---- */
  const int srow = tid >> 3;                       /* 0..63 */
  const int sxor = ((tid & 7) ^ (srow & 7)) * 16;  /* byte slot swizzle */
  const char* aptr[4];
#pragma unroll
  for (int i = 0; i < 4; ++i) {
    int rg = row0 + i * 64 + srow;
    long rowElem;
    if (rg < rows) {
      unsigned e = tlist[toff + (rg >> 3)];
      unsigned n = e >> 16;
      int b = rg & 7;
      rowElem = (n == 0xFFFFu) ? ZROW * (long)DIN
                               : ((long)(b * N_ + (int)n)) * DIN;
    } else {
      rowElem = ZROW * (long)DIN;
    }
    aptr[i] = (const char*)(wsP + rowElem) + sxor;
  }
  const char* bptr[2];
#pragma unroll
  for (int i = 0; i < 2; ++i)
    bptr[i] = (const char*)(wsW +
              ((long)l * DOUT + nt * BN + i * 64 + srow) * DIN) + sxor;

/* LDS dest: wave-uniform base, HW adds lane*16 (verified round 0) */
#define STAGE_A(i, kt, nb) \
  gload_lds16(aptr[i] + (kt) * 128, (char*)As[nb] + (i) * 8192 + w * 1024)
#define STAGE_B(i, kt, nb) \
  gload_lds16(bptr[i] + (kt) * 128, (char*)Bs[nb] + (i) * 8192 + w * 1024)

  /* ---- fragment read offsets (same XOR on the read side) ---- */
  const int arb = (wm * 64 + (lane & 15)) * BK;   /* row&7 == lane&7 */
  const int brb = (wn * 64 + (lane & 15)) * BK;
  const int ax0 = (((lane >> 4) + 0) ^ (lane & 7)) * 8;  /* k2=0 slot */
  const int ax1 = (((lane >> 4) + 4) ^ (lane & 7)) * 8;  /* k2=1 slot */

  f32x4 acc[4][4];
#pragma unroll
  for (int m = 0; m < 4; ++m)
#pragma unroll
    for (int n = 0; n < 4; ++n)
      acc[m][n] = (f32x4){0.f, 0.f, 0.f, 0.f};

  /* ---- prologue: stage tiles 0,1 into bufs 0,1 ---- */
  STAGE_A(0, 0, 0); STAGE_A(1, 0, 0); STAGE_A(2, 0, 0);
  STAGE_A(3, 0, 0); STAGE_B(0, 0, 0); STAGE_B(1, 0, 0);
  STAGE_A(0, 1, 1); STAGE_A(1, 1, 1); STAGE_A(2, 1, 1);
  STAGE_A(3, 1, 1); STAGE_B(0, 1, 1); STAGE_B(1, 1, 1);
  asm volatile("s_waitcnt vmcnt(6)" ::: "memory");  /* tile 0 complete */
  bar();

  int buf = 0;
  for (int t = 0; t < NKT; ++t) {
    const unsigned short* Ab = As[buf];
    const unsigned short* Bb = Bs[buf];
    const int nb = (buf >= 1) ? buf - 1 : buf + 2;   /* (t+2)%3 */
    const int kt2 = t + 2;

    short8 af[4][2], bf[4][2];

    /* ---------- phase 1: all af + bf[0..1]; stage A0-A2 of t+2 ---------- */
#pragma unroll
    for (int m = 0; m < 4; ++m) {
      af[m][0] = *(const short8*)(Ab + arb + m * 1024 + ax0);
      af[m][1] = *(const short8*)(Ab + arb + m * 1024 + ax1);
    }
#pragma unroll
    for (int n = 0; n < 2; ++n) {
      bf[n][0] = *(const short8*)(Bb + brb + n * 1024 + ax0);
      bf[n][1] = *(const short8*)(Bb + brb + n * 1024 + ax1);
    }
    if (kt2 < NKT) { STAGE_A(0, kt2, nb); STAGE_A(1, kt2, nb); STAGE_A(2, kt2, nb); }
    bar();
    __builtin_amdgcn_s_setprio(1);
#pragma unroll
    for (int n = 0; n < 2; ++n)
#pragma unroll
      for (int m = 0; m < 4; ++m) {
        acc[m][n] = __builtin_amdgcn_mfma_f32_16x16x32_bf16(af[m][0], bf[n][0], acc[m][n], 0, 0, 0);
        acc[m][n] = __builtin_amdgcn_mfma_f32_16x16x32_bf16(af[m][1], bf[n][1], acc[m][n], 0, 0, 0);
      }
    __builtin_amdgcn_s_setprio(0);
    bar();

    /* ---------- phase 2: bf[2..3]; stage A3,B0,B1 of t+2 ---------- */
#pragma unroll
    for (int n = 2; n < 4; ++n) {
      bf[n][0] = *(const short8*)(Bb + brb + n * 1024 + ax0);
      bf[n][1] = *(const short8*)(Bb + brb + n * 1024 + ax1);
    }
    if (kt2 < NKT) { STAGE_A(3, kt2, nb); STAGE_B(0, kt2, nb); STAGE_B(1, kt2, nb); }
    bar();
    __builtin_amdgcn_s_setprio(1);
#pragma unroll
    for (int n = 2; n < 4; ++n)
#pragma unroll
      for (int m = 0; m < 4; ++m) {
        acc[m][n] = __builtin_amdgcn_mfma_f32_16x16x32_bf16(af[m][0], bf[n][0], acc[m][n], 0, 0, 0);
        acc[m][n] = __builtin_amdgcn_mfma_f32_16x16x32_bf16(af[m][1], bf[n][1], acc[m][n], 0, 0, 0);
      }
    __builtin_amdgcn_s_setprio(0);
    /* counted drain: allow t+2's 6 loads in flight, force t+1's complete */
    if (t <= NKT - 3)      asm volatile("s_waitcnt vmcnt(6)" ::: "memory");
    else if (t == NKT - 2) asm volatile("s_waitcnt vmcnt(0)" ::: "memory");
    bar();

    buf = (buf == 2) ? 0 : buf + 1;
  }

  /* ---- epilogue: C/D layout col=lane&15, row=(lane>>4)*4+j ---- */
#pragma unroll
  for (int m = 0; m < 4; ++m) {
#pragma unroll
    for (int j = 0; j < 4; ++j) {
      int rt = wm * 64 + m * 16 + (lane >> 4) * 4 + j;
      int rg = row0 + rt;
      if (rg >= rows) continue;
      unsigned e = tlist[toff + (rg >> 3)];
      int b = rg & 7;
      int tt = (int)(e & 0xFFFFu);
      float* orow = out + ((long)b * T_ + tt) * DOUT + nt * BN + wn * 64 + (lane & 15);
#pragma unroll
      for (int n = 0; n < 4; ++n)
        orow[n * 16] = acc[m][n][j];
    }
  }
#undef STAGE_A
#undef STAGE_B
}

/* ---------------- launch ---------------- */
extern "C" void kernel_launch(void* const* d_in, const int* in_sizes, int n_in,
                              void* d_out, int out_size, void* d_ws, size_t ws_size,
                              hipStream_t stream) {
  const float* pooled = (const float*)d_in[0];
  const float* W      = (const float*)d_in[1];
  const int*   pidx   = (const int*)d_in[2];
  float* out = (float*)d_out;

  char* ws = (char*)d_ws;
  unsigned short* wsP = (unsigned short*)(ws);
  unsigned short* wsW = (unsigned short*)(ws + WS_W_OFF);
  int* meta  = (int*)(ws + WS_META_OFF);
  int* map   = meta;
  unsigned* tlist = (unsigned*)(meta + T_);
  int* goff  = meta + 2 * T_;
  int* grows = meta + 2 * T_ + 16;
  unsigned* table = (unsigned*)(meta + 2 * T_ + 32);
  int* ntiles = meta + 2 * T_ + 32 + MT_MAX;

  k_convert<<<2048, 256, 0, stream>>>(pooled, W, wsP, wsW);
  k_map<<<(T_ + 255) / 256, 256, 0, stream>>>(pidx, map);
  k_group<<<1, 256, 0, stream>>>(map, tlist, goff, grows, table, ntiles);
  k_gemm<<<MT_MAX * NB, 512, 0, stream>>>(wsP, wsW, tlist, goff, grows, table,
                                          ntiles, out);
}